// Round 3
// baseline (133.753 us; speedup 1.0000x reference)
//
#include <hip/hip_runtime.h>
#include <hip/hip_bf16.h>
#include <math.h>

// Problem constants: N=6, B=2, H=12, T=1024, D=768, scaling = 1/sqrt(64) = 0.125
#define PN 6
#define PB 2
#define PH 12
#define PT 1024
#define PD 768

#define NBLOCKS 3072
#define NTHREADS 256
// stride = NBLOCKS*NTHREADS = 786432 f4; per-b span BSTRIDE4 = 3145728 = 4*stride
#define ITERS_PER_B 4

typedef float f4 __attribute__((ext_vector_type(4)));

// ---------------------------------------------------------------------------
// Kernel 1: per (b,t) row compute e_scaled[n] = 0.125 * exp(a[n]) where
//   a = GELU_exact(RMSNorm(x) @ w1) @ w2 + bias
// One wave (64 lanes) per row. Output layout: e_ws[n * (B*T) + b*T + t].
// ---------------------------------------------------------------------------
__global__ __launch_bounds__(64) void compute_e_kernel(
    const float* __restrict__ x,      // [B*T, D]
    const float* __restrict__ nw,     // [D]
    const float* __restrict__ w1,     // [D, N] row-major
    const float* __restrict__ w2,     // [N, N] row-major
    const float* __restrict__ bias,   // [N]
    float* __restrict__ e_out)        // [N, B*T]
{
    const int row  = blockIdx.x;          // 0 .. B*T-1
    const int lane = threadIdx.x;         // 0 .. 63
    const float* xr = x + (size_t)row * PD;

    float xs[12];
    float sumsq = 0.0f;
#pragma unroll
    for (int k = 0; k < 12; ++k) {
        float v = xr[lane + 64 * k];
        xs[k] = v;
        sumsq += v * v;
    }
#pragma unroll
    for (int off = 32; off; off >>= 1) sumsq += __shfl_xor(sumsq, off, 64);

    const float eps = 1.1920928955078125e-07f;  // float32 machine eps
    const float inv = rsqrtf(sumsq * (1.0f / (float)PD) + eps);

    float p[PN] = {0.f, 0.f, 0.f, 0.f, 0.f, 0.f};
#pragma unroll
    for (int k = 0; k < 12; ++k) {
        const int d = lane + 64 * k;
        const float nv = xs[k] * inv * nw[d];
#pragma unroll
        for (int n = 0; n < PN; ++n) p[n] += nv * w1[d * PN + n];
    }
#pragma unroll
    for (int n = 0; n < PN; ++n) {
#pragma unroll
        for (int off = 32; off; off >>= 1) p[n] += __shfl_xor(p[n], off, 64);
    }

    if (lane == 0) {
        float g[PN];
#pragma unroll
        for (int n = 0; n < PN; ++n) {
            const float v = p[n];
            g[n] = 0.5f * v * (1.0f + erff(v * 0.7071067811865476f));
        }
#pragma unroll
        for (int j = 0; j < PN; ++j) {
            float a = bias[j];
#pragma unroll
            for (int n = 0; n < PN; ++n) a += g[n] * w2[n * PN + j];
            e_out[(size_t)j * (PB * PT) + row] = 0.125f * expf(a);
        }
    }
}

// ---------------------------------------------------------------------------
// Kernel 2: out[i] = sum_n qk[n*PLANE + i] * e[n, b(i), t(i)]
// 3072 blocks x 256 threads -> exactly 4 iterations per b, fully unrolled:
// 24 clustered nontemporal loads, FMAs, 4 clustered stores. All addresses
// are 32-bit offsets from uniform per-plane bases (SADDR form).
// ---------------------------------------------------------------------------
__global__ __launch_bounds__(NTHREADS) void combine_kernel(
    const float* __restrict__ qk,   // [N, B, H, T, T]
    const float* __restrict__ e,    // [N, B*T]
    float* __restrict__ out)        // [B, H, T, T]
{
    const uint32_t T4       = PT / 4;                        // 256
    const uint32_t PLANE4   = (uint32_t)PB * PH * PT * T4;   // 6,291,456
    const uint32_t BSTRIDE4 = (uint32_t)PH * PT * T4;        // 3,145,728
    const uint32_t stride   = (uint32_t)NBLOCKS * NTHREADS;  // 786,432

    const f4* q4 = (const f4*)qk;
    const f4* e4 = (const f4*)e;
    f4* o4 = (f4*)out;

    const uint32_t tid = (uint32_t)blockIdx.x * NTHREADS + threadIdx.x;
    const uint32_t t4  = tid & (T4 - 1);   // invariant: stride % 256 == 0

#pragma unroll
    for (uint32_t b = 0; b < PB; ++b) {
        // hoist e-table values for this (b, t4)
        f4 ev[PN];
#pragma unroll
        for (uint32_t n = 0; n < PN; ++n)
            ev[n] = e4[n * (PB * T4) + b * T4 + t4];

        const uint32_t base = b * BSTRIDE4 + tid;

        // cluster all loads
        f4 qv[ITERS_PER_B][PN];
#pragma unroll
        for (uint32_t j = 0; j < ITERS_PER_B; ++j) {
            const uint32_t i4 = base + j * stride;
#pragma unroll
            for (uint32_t n = 0; n < PN; ++n)
                qv[j][n] = __builtin_nontemporal_load(&q4[n * PLANE4 + i4]);
        }

        // compute + cluster stores
#pragma unroll
        for (uint32_t j = 0; j < ITERS_PER_B; ++j) {
            f4 acc = qv[j][0] * ev[0];
#pragma unroll
            for (uint32_t n = 1; n < PN; ++n) acc += qv[j][n] * ev[n];
            __builtin_nontemporal_store(acc, &o4[base + j * stride]);
        }
    }
}

extern "C" void kernel_launch(void* const* d_in, const int* in_sizes, int n_in,
                              void* d_out, int out_size, void* d_ws, size_t ws_size,
                              hipStream_t stream) {
    const float* qk   = (const float*)d_in[0];  // [N,B,H,T,T]
    const float* x    = (const float*)d_in[1];  // [B,T,D]
    const float* nw   = (const float*)d_in[2];  // [D]
    const float* w1   = (const float*)d_in[3];  // [D,N]
    const float* w2   = (const float*)d_in[4];  // [N,N]
    const float* bias = (const float*)d_in[5];  // [N]
    float* out = (float*)d_out;

    float* e_ws = (float*)d_ws;                 // N*B*T floats = 48 KB

    compute_e_kernel<<<PB * PT, 64, 0, stream>>>(x, nw, w1, w2, bias, e_ws);
    combine_kernel<<<NBLOCKS, NTHREADS, 0, stream>>>(qk, e_ws, out);
}